// Round 18
// baseline (127.494 us; speedup 1.0000x reference)
//
#include <hip/hip_runtime.h>

#define BSZ 2
#define SEQ 2048
#define NH 16
#define DHD 64
#define HDIM 1024   // NH*DHD
#define FS 1024     // input feature size
#define MR (BSZ*SEQ) // 4096
#define L2E 1.4426950408889634f

typedef __bf16 bf16x8 __attribute__((ext_vector_type(8)));
typedef __bf16 bf16x2t __attribute__((ext_vector_type(2)));
typedef float f32x4 __attribute__((ext_vector_type(4)));
typedef float f32x16 __attribute__((ext_vector_type(16)));
typedef unsigned short u16;
typedef unsigned int u32;
typedef u32 u32x4 __attribute__((ext_vector_type(4)));

__device__ __forceinline__ u16 f2bf(float f) {
  u32 x = __float_as_uint(f);
  return (u16)((x + 0x7fffu + ((x >> 16) & 1u)) >> 16);
}

__device__ __forceinline__ u32 pack2bf(float a, float b) {
  bf16x2t t = {(__bf16)a, (__bf16)b};
  return __builtin_bit_cast(u32, t);
}

__device__ __forceinline__ void gload16(const void* g, void* l) {
  __builtin_amdgcn_global_load_lds(
      (const __attribute__((address_space(1))) u32*)g,
      (__attribute__((address_space(3))) u32*)l, 16, 0, 0);
}

// ------- 4x W[K][N] fp32 -> WT[N][K] bf16 (one launch; dsts contiguous) ----
__global__ __launch_bounds__(256) void transw4_k(
    const float* __restrict__ W0, const float* __restrict__ W1,
    const float* __restrict__ W2, const float* __restrict__ W3,
    u16* __restrict__ WTbase) {
  __shared__ float t[32][33];
  const int z = blockIdx.z;
  const float* W = z == 0 ? W0 : z == 1 ? W1 : z == 2 ? W2 : W3;
  u16* WT = WTbase + (size_t)z * FS * HDIM;
  const int tx = threadIdx.x, ty = threadIdx.y;
  const int c0 = blockIdx.x * 32, r0 = blockIdx.y * 32;
#pragma unroll
  for (int i = 0; i < 4; i++)
    t[ty + 8 * i][tx] = W[(size_t)(r0 + ty + 8 * i) * FS + c0 + tx];
  __syncthreads();
#pragma unroll
  for (int i = 0; i < 4; i++)
    WT[(size_t)(c0 + ty + 8 * i) * FS + r0 + tx] = f2bf(t[tx][ty + 8 * i]);
}

// -------- grouped QKV projection GEMM: grid (256, 3) --------
// Full dbuf (aL+bL), ONE __syncthreads per K-step (R17 gemm_out schedule):
// bar -> issue B(kt+1)->bL[nxt] -> cvt A(kt+1) regs -> ds_write aL[nxt]
// -> issue A(kt+2) loads -> ds_read [cur] + MFMA.  All staging latency
// hides under the MFMA phase; drained by the next barrier.
// Block mapping keeps all 8 n-tiles of an A m-panel on ONE XCD.
__global__ __launch_bounds__(256, 2) void gemmQKV_k(
    const float* __restrict__ qf32, const float* __restrict__ kf32,
    const float* __restrict__ vf32, const u16* __restrict__ WTbase,
    const float* __restrict__ bq, const float* __restrict__ bk,
    const float* __restrict__ bv, u16* __restrict__ QKbase,
    u16* __restrict__ VpT) {
  __shared__ u16 aL[2][128 * 64];
  __shared__ u16 bL[2][128 * 64];
  const int grp = blockIdx.y;
  const float* Af = grp == 0 ? qf32 : grp == 1 ? kf32 : vf32;
  const u16* BT = WTbase + (size_t)grp * FS * HDIM;
  const float* bias = grp == 0 ? bq : grp == 1 ? bk : bv;
  const int bx = blockIdx.x;
  const int m0 = (4 * (bx & 7) + (bx >> 6)) << 7;   // same-XCD m-panel group
  const int n0 = ((bx >> 3) & 7) << 7;
  const int tid = threadIdx.x, w = tid >> 6, lane = tid & 63;
  const int wr = ((w >> 1) << 6), wc = ((w & 1) << 6);
  const int li = lane & 15, g = lane >> 4;

  f32x4 acc[4][4];
#pragma unroll
  for (int i = 0; i < 4; i++)
#pragma unroll
    for (int j = 0; j < 4; j++) acc[i][j] = (f32x4){0.f, 0.f, 0.f, 0.f};

  // per-chunk sources (constant per thread; step by k)
  const float* asrc[4];
  const u16* bsrc[4];
  int ldoff[4];
#pragma unroll
  for (int j = 0; j < 4; j++) {
    const int c = w * 4 + j;
    const int r = c * 8 + (lane >> 3);
    const int sc = (lane & 7) ^ (r & 7);
    asrc[j] = Af + (size_t)(m0 + r) * FS + sc * 8;
    bsrc[j] = BT + (size_t)(n0 + r) * FS + sc * 8;
    ldoff[j] = c * 1024;
  }

  // prologue: B(0) -> bL[0]; A(0) regs -> cvt -> aL[0]; A(1) regs
  float4 ar0[4], ar1[4];
#pragma unroll
  for (int j = 0; j < 4; j++) gload16(bsrc[j], (char*)bL[0] + ldoff[j]);
#pragma unroll
  for (int j = 0; j < 4; j++) {
    ar0[j] = *(const float4*)(asrc[j]);
    ar1[j] = *(const float4*)(asrc[j] + 4);
  }
#pragma unroll
  for (int j = 0; j < 4; j++) {
    u32x4 pk;
    pk[0] = pack2bf(ar0[j].x, ar0[j].y);
    pk[1] = pack2bf(ar0[j].z, ar0[j].w);
    pk[2] = pack2bf(ar1[j].x, ar1[j].y);
    pk[3] = pack2bf(ar1[j].z, ar1[j].w);
    *(u32x4*)((char*)aL[0] + ldoff[j] + lane * 16) = pk;
  }
#pragma unroll
  for (int j = 0; j < 4; j++) {
    ar0[j] = *(const float4*)(asrc[j] + 64);
    ar1[j] = *(const float4*)(asrc[j] + 68);
  }

  for (int kt = 0; kt < 16; kt++) {
    const int cur = kt & 1;
    __syncthreads();  // [cur] staged for all waves; prev reads of [nxt] done
    if (kt + 1 < 16) {
      const int ko = (kt + 1) * 64;
      // B(kt+1) -> bL[nxt]
#pragma unroll
      for (int j = 0; j < 4; j++)
        gload16(bsrc[j] + ko, (char*)bL[cur ^ 1] + ldoff[j]);
      // cvt A(kt+1) regs (loaded last phase) -> aL[nxt]
#pragma unroll
      for (int j = 0; j < 4; j++) {
        u32x4 pk;
        pk[0] = pack2bf(ar0[j].x, ar0[j].y);
        pk[1] = pack2bf(ar0[j].z, ar0[j].w);
        pk[2] = pack2bf(ar1[j].x, ar1[j].y);
        pk[3] = pack2bf(ar1[j].z, ar1[j].w);
        *(u32x4*)((char*)aL[cur ^ 1] + ldoff[j] + lane * 16) = pk;
      }
      // issue A(kt+2) register loads
      if (kt + 2 < 16) {
        const int ko2 = (kt + 2) * 64;
#pragma unroll
        for (int j = 0; j < 4; j++) {
          ar0[j] = *(const float4*)(asrc[j] + ko2);
          ar1[j] = *(const float4*)(asrc[j] + ko2 + 4);
        }
      }
    }
    // ds_read fragments + MFMA on [cur]
    bf16x8 af[2][4], bfr[2][4];
#pragma unroll
    for (int ks = 0; ks < 2; ks++) {
#pragma unroll
      for (int mf = 0; mf < 4; mf++) {
        const int r = wr + mf * 16 + li;
        const int sl = (g + 4 * ks) ^ (r & 7);
        af[ks][mf] = *(const bf16x8*)((const char*)aL[cur] + r * 128 + sl * 16);
      }
#pragma unroll
      for (int nf = 0; nf < 4; nf++) {
        const int r = wc + nf * 16 + li;
        const int sl = (g + 4 * ks) ^ (r & 7);
        bfr[ks][nf] = *(const bf16x8*)((const char*)bL[cur] + r * 128 + sl * 16);
      }
    }
#pragma unroll
    for (int ks = 0; ks < 2; ks++)
#pragma unroll
      for (int mf = 0; mf < 4; mf++)
#pragma unroll
        for (int nf = 0; nf < 4; nf++)
          acc[mf][nf] = __builtin_amdgcn_mfma_f32_16x16x32_bf16(
              af[ks][mf], bfr[ks][nf], acc[mf][nf], 0, 0, 0);
  }

  if (grp < 2) {
    const float osc = grp == 0 ? 0.125f * L2E : 1.0f;
    u16* C = QKbase + (size_t)grp * MR * HDIM;
#pragma unroll
    for (int mf = 0; mf < 4; mf++)
#pragma unroll
      for (int nf = 0; nf < 4; nf++) {
        const int n = n0 + wc + nf * 16 + li;
        const float bvl = bias[n];
#pragma unroll
        for (int r4 = 0; r4 < 4; r4++) {
          const int m = m0 + wr + mf * 16 + g * 4 + r4;
          C[(size_t)m * HDIM + n] = f2bf((acc[mf][nf][r4] + bvl) * osc);
        }
      }
  } else {
    // V: write transposed per head -> VpT[((b*NH+h)*DHD+d)][kv]
#pragma unroll
    for (int mf = 0; mf < 4; mf++)
#pragma unroll
      for (int nf = 0; nf < 4; nf++) {
        const int n = n0 + wc + nf * 16 + li;
        const float bvl = bias[n];
        const int m = m0 + wr + mf * 16 + g * 4;
        const int bb = m >> 11, kv = m & 2047;
        ushort4 o;
        o.x = f2bf(acc[mf][nf][0] + bvl);
        o.y = f2bf(acc[mf][nf][1] + bvl);
        o.z = f2bf(acc[mf][nf][2] + bvl);
        o.w = f2bf(acc[mf][nf][3] + bvl);
        *(ushort4*)(VpT +
                    ((size_t)(bb * NH + (n >> 6)) * DHD + (n & 63)) * SEQ + kv) = o;
      }
  }
}

// ---------------- output GEMM: out[M][N] = Hd @ WoT^T + bo (fp32) ----------
// R17 version: 128x64 tiles (grid 512), full dbuf, one barrier per K-step.
__global__ __launch_bounds__(256, 2) void gemm_out_k(
    const u16* __restrict__ A, const u16* __restrict__ BT,
    const float* __restrict__ bias, float* __restrict__ C) {
  __shared__ u16 aL[2][128 * 64];
  __shared__ u16 bL[2][64 * 64];
  const int bx = blockIdx.x;
  const int m0 = ((bx & 7) * 4 + (bx >> 7)) << 7;
  const int n0 = ((bx >> 3) & 15) << 6;
  const int tid = threadIdx.x, w = tid >> 6, lane = tid & 63;
  const int wr = ((w >> 1) << 6), wc = ((w & 1) << 5);  // 2x2 of 64x32
  const int li = lane & 15, g = lane >> 4;

  f32x4 acc[4][2];
#pragma unroll
  for (int i = 0; i < 4; i++)
#pragma unroll
    for (int j = 0; j < 2; j++) acc[i][j] = (f32x4){0.f, 0.f, 0.f, 0.f};

  const u16* asrc[4];
  const u16* bsrc[2];
  int aoff[4], boff[2];
#pragma unroll
  for (int j = 0; j < 4; j++) {
    const int c = w * 4 + j;
    const int r = c * 8 + (lane >> 3);
    const int sc = (lane & 7) ^ (r & 7);
    asrc[j] = A + (size_t)(m0 + r) * HDIM + sc * 8;
    aoff[j] = c * 1024;
  }
#pragma unroll
  for (int j = 0; j < 2; j++) {
    const int c = w * 2 + j;
    const int r = c * 8 + (lane >> 3);
    const int sc = (lane & 7) ^ (r & 7);
    bsrc[j] = BT + (size_t)(n0 + r) * HDIM + sc * 8;
    boff[j] = c * 1024;
  }

  auto stage = [&](int kt, int buf) {
    const int ko = kt * 64;
#pragma unroll
    for (int j = 0; j < 4; j++)
      gload16(asrc[j] + ko, (char*)aL[buf] + aoff[j]);
#pragma unroll
    for (int j = 0; j < 2; j++)
      gload16(bsrc[j] + ko, (char*)bL[buf] + boff[j]);
  };

  stage(0, 0);

  for (int kt = 0; kt < 16; kt++) {
    const int cur = kt & 1;
    __syncthreads();  // drains stage(kt); prev compute reads of cur done
    if (kt + 1 < 16) stage(kt + 1, cur ^ 1);
    bf16x8 af[2][4], bfr[2][2];
#pragma unroll
    for (int ks = 0; ks < 2; ks++) {
#pragma unroll
      for (int mf = 0; mf < 4; mf++) {
        const int r = wr + mf * 16 + li;
        const int sl = (g + 4 * ks) ^ (r & 7);
        af[ks][mf] = *(const bf16x8*)((const char*)aL[cur] + r * 128 + sl * 16);
      }
#pragma unroll
      for (int nf = 0; nf < 2; nf++) {
        const int r = wc + nf * 16 + li;
        const int sl = (g + 4 * ks) ^ (r & 7);
        bfr[ks][nf] = *(const bf16x8*)((const char*)bL[cur] + r * 128 + sl * 16);
      }
    }
#pragma unroll
    for (int ks = 0; ks < 2; ks++)
#pragma unroll
      for (int mf = 0; mf < 4; mf++)
#pragma unroll
        for (int nf = 0; nf < 2; nf++)
          acc[mf][nf] = __builtin_amdgcn_mfma_f32_16x16x32_bf16(
              af[ks][mf], bfr[ks][nf], acc[mf][nf], 0, 0, 0);
  }

#pragma unroll
  for (int mf = 0; mf < 4; mf++)
#pragma unroll
    for (int nf = 0; nf < 2; nf++) {
      const int n = n0 + wc + nf * 16 + li;
      const float bvl = bias[n];
#pragma unroll
      for (int r4 = 0; r4 < 4; r4++) {
        const int m = m0 + wr + mf * 16 + g * 4 + r4;
        C[(size_t)m * HDIM + n] = acc[mf][nf][r4] + bvl;
      }
    }
}

// ------- flash attention: 2-way kv-split, 8 waves, 32x32 MFMA, QBLK=128 ----
// R13/R16 version (best measured: 56.5us).  Frozen.
__global__ __launch_bounds__(512, 1) void attn_k(
    const u16* __restrict__ Qp, const u16* __restrict__ Kp,
    const u16* __restrict__ VpT, u16* __restrict__ Hd) {
  __shared__ u16 kbuf[4][64 * 64];   // K [kv][d], swizzled; [0..1] = Q staging
  __shared__ u16 vbuf[4][64 * 64];   // V^T [d][kv], swizzled

  const int bid = blockIdx.x;
  const int swz = (bid & 7) * 64 + (bid >> 3);  // XCD swizzle (512 = 8*64)
  const int qb = swz & 15;
  const int h = (swz >> 4) & 15;
  const int b = swz >> 8;
  const int tid = threadIdx.x, w = tid >> 6, lane = tid & 63;
  const int sel = w >> 2, g3 = w & 3;
  const int q32 = lane & 31, hi = lane >> 5;
  const int q0 = qb << 7;
  const size_t qbase = (size_t)(b * SEQ + q0) * HDIM + (size_t)h * DHD;
  const size_t kbase = (size_t)(b * SEQ) * HDIM + (size_t)h * DHD;
  const size_t vtbase = (size_t)(b * NH + h) * DHD * SEQ;

  const int rr = lane >> 3;
  const int sc8 = ((lane & 7) ^ rr) * 8;
  const int fkey = (q32 & 7) << 4;

  // ---- stage Q (16KB = kbuf[0..1]) with all 8 waves, read frags, release --
#pragma unroll
  for (int j = 0; j < 2; j++) {
    const int c = w * 2 + j;                // 16 chunks of 8 rows
    const int r = c * 8 + rr;               // q row 0..127
    gload16(Qp + qbase + (size_t)r * HDIM + sc8, (char*)kbuf + c * 1024);
  }
  __syncthreads();
  bf16x8 qf[4];
  {
    const char* qbp = (const char*)kbuf + (g3 * 32 + q32) * 128;
#pragma unroll
    for (int ds = 0; ds < 4; ds++)
      qf[ds] = *(const bf16x8*)(qbp + ((32 * ds + 16 * hi) ^ fkey));
  }
  __syncthreads();

  float mrun = -1e30f, lrun = 0.f;
  f32x16 o0, o1;
#pragma unroll
  for (int i = 0; i < 16; i++) { o0[i] = 0.f; o1[i] = 0.f; }

  // running staging pointers (strength-reduced; advance by const stride)
  const int c0j = g3 * 2;                   // this wave's first chunk
  const int r0r = c0j * 8 + rr;             // its row in the tile
  const u16* kp0 = Kp + kbase + (size_t)(r0r + sel * 64) * HDIM + sc8;
  const u16* kp1 = kp0 + (size_t)8 * HDIM;
  const u16* vp0 = VpT + vtbase + (size_t)r0r * SEQ + sel * 64 + sc8;
  const u16* vp1 = vp0 + (size_t)8 * SEQ;
  const int ldk0 = c0j * 1024, ldk1 = (c0j + 1) * 1024;

  auto stage2 = [&](int buf) {
    gload16(kp0, (char*)kbuf[buf] + ldk0);
    gload16(kp1, (char*)kbuf[buf] + ldk1);
    gload16(vp0, (char*)vbuf[buf] + ldk0);
    gload16(vp1, (char*)vbuf[buf] + ldk1);
    kp0 += (size_t)128 * HDIM;
    kp1 += (size_t)128 * HDIM;
    vp0 += 128;
    vp1 += 128;
  };

  stage2(sel);

#pragma unroll 1
  for (int p = 0; p < SEQ / 128; p++) {
    __syncthreads();  // pair (2p,2p+1) staged; prev reads of those slots done
    if (p + 1 < SEQ / 128) stage2(sel + 2 * ((p + 1) & 1));
    const char* kl = (const char*)kbuf[sel + 2 * (p & 1)];
    const char* vl = (const char*)vbuf[sel + 2 * (p & 1)];

    // ---- S^T = K @ Q^T : C[kv 0-31 | 32-63][q=q32] ----
    f32x16 s0, s1;
#pragma unroll
    for (int i = 0; i < 16; i++) { s0[i] = 0.f; s1[i] = 0.f; }
#pragma unroll
    for (int ds = 0; ds < 4; ds++) {
      const int off = (32 * ds + 16 * hi) ^ fkey;
      const bf16x8 ka = *(const bf16x8*)(kl + q32 * 128 + off);
      const bf16x8 kb2 = *(const bf16x8*)(kl + (32 + q32) * 128 + off);
      s0 = __builtin_amdgcn_mfma_f32_32x32x16_bf16(ka, qf[ds], s0, 0, 0, 0);
      s1 = __builtin_amdgcn_mfma_f32_32x32x16_bf16(kb2, qf[ds], s1, 0, 0, 0);
    }

    // ---- online softmax, tree reductions, defer-max THR=8 (log2 units) ----
    float mt[16];
#pragma unroll
    for (int i = 0; i < 16; i++) mt[i] = fmaxf(s0[i], s1[i]);
#pragma unroll
    for (int i = 0; i < 8; i++) mt[i] = fmaxf(mt[i], mt[i + 8]);
#pragma unroll
    for (int i = 0; i < 4; i++) mt[i] = fmaxf(mt[i], mt[i + 4]);
    float mx = fmaxf(fmaxf(mt[0], mt[1]), fmaxf(mt[2], mt[3]));
    mx = fmaxf(mx, __shfl_xor(mx, 32));
    if (!__all(mx <= mrun + 8.0f)) {
      const float mnew = fmaxf(mrun, mx);
      const float scl = __builtin_amdgcn_exp2f(mrun - mnew);
      mrun = mnew;
      lrun *= scl;
#pragma unroll
      for (int i = 0; i < 16; i++) { o0[i] *= scl; o1[i] *= scl; }
    }
    float p0[16], p1[16];
#pragma unroll
    for (int i = 0; i < 16; i++) {
      p0[i] = __builtin_amdgcn_exp2f(s0[i] - mrun);
      p1[i] = __builtin_amdgcn_exp2f(s1[i] - mrun);
    }
    float st[16];
#pragma unroll
    for (int i = 0; i < 16; i++) st[i] = p0[i] + p1[i];
#pragma unroll
    for (int i = 0; i < 8; i++) st[i] += st[i + 8];
#pragma unroll
    for (int i = 0; i < 4; i++) st[i] += st[i + 4];
    float rs = (st[0] + st[1]) + (st[2] + st[3]);
    rs += __shfl_xor(rs, 32);
    lrun += rs;

    // ---- O^T += V^T @ P^T ; P B-frag via permlane32_swap (verified R7) ----
#pragma unroll
    for (int kvs = 0; kvs < 4; kvs++) {
      const float* ps = (kvs < 2) ? p0 : p1;
      const int rb = (kvs & 1) * 8;
      u32 w01 = pack2bf(ps[rb + 0], ps[rb + 1]);
      u32 w23 = pack2bf(ps[rb + 2], ps[rb + 3]);
      u32 w45 = pack2bf(ps[rb + 4], ps[rb + 5]);
      u32 w67 = pack2bf(ps[rb + 6], ps[rb + 7]);
      asm("v_permlane32_swap_b32 %0, %1" : "+v"(w01), "+v"(w45));
      asm("v_permlane32_swap_b32 %0, %1" : "+v"(w23), "+v"(w67));
      u32x4 uw = {w01, w23, w45, w67};
      const bf16x8 pf = __builtin_bit_cast(bf16x8, uw);
      const int off = (32 * kvs + 16 * hi) ^ fkey;
      const bf16x8 va = *(const bf16x8*)(vl + q32 * 128 + off);
      const bf16x8 vb2 = *(const bf16x8*)(vl + (32 + q32) * 128 + off);
      o0 = __builtin_amdgcn_mfma_f32_32x32x16_bf16(va, pf, o0, 0, 0, 0);
      o1 = __builtin_amdgcn_mfma_f32_32x32x16_bf16(vb2, pf, o1, 0, 0, 0);
    }
  }

  // ---- merge kv-split pairs (waves g3,sel=1 -> g3,sel=0) via LDS ----
  __syncthreads();  // all compute reads of kbuf/vbuf done
  char* mbase = (char*)kbuf + (g3 * 64 + lane) * 144;  // 4*64*144 = 36864 B
  if (sel == 1) {
#pragma unroll
    for (int i = 0; i < 4; i++) {
      *(f32x4*)(mbase + i * 16) =
          (f32x4){o0[4 * i], o0[4 * i + 1], o0[4 * i + 2], o0[4 * i + 3]};
      *(f32x4*)(mbase + 64 + i * 16) =
          (f32x4){o1[4 * i], o1[4 * i + 1], o1[4 * i + 2], o1[4 * i + 3]};
    }
    *(float*)(mbase + 128) = mrun;
    *(float*)(mbase + 132) = lrun;
  }
  __syncthreads();
  if (sel == 0) {
    const float m2 = *(const float*)(mbase + 128);
    const float l2 = *(const float*)(mbase + 132);
    const float ms = fmaxf(mrun, m2);
    const float f1 = __builtin_amdgcn_exp2f(mrun - ms);
    const float f2 = __builtin_amdgcn_exp2f(m2 - ms);
    const float inv = 1.f / (lrun * f1 + l2 * f2);
    const int q = q0 + g3 * 32 + q32;
    u16* orow = Hd + (size_t)(b * SEQ + q) * HDIM + (size_t)h * DHD;
#pragma unroll
    for (int rg = 0; rg < 4; rg++) {
      const f32x4 a2 = *(const f32x4*)(mbase + rg * 16);
      const f32x4 b2 = *(const f32x4*)(mbase + 64 + rg * 16);
      ushort4 ov;
      ov.x = f2bf((o0[4 * rg + 0] * f1 + a2[0] * f2) * inv);
      ov.y = f2bf((o0[4 * rg + 1] * f1 + a2[1] * f2) * inv);
      ov.z = f2bf((o0[4 * rg + 2] * f1 + a2[2] * f2) * inv);
      ov.w = f2bf((o0[4 * rg + 3] * f1 + a2[3] * f2) * inv);
      *(ushort4*)(orow + 8 * rg + 4 * hi) = ov;
      ushort4 ow;
      ow.x = f2bf((o1[4 * rg + 0] * f1 + b2[0] * f2) * inv);
      ow.y = f2bf((o1[4 * rg + 1] * f1 + b2[1] * f2) * inv);
      ow.z = f2bf((o1[4 * rg + 2] * f1 + b2[2] * f2) * inv);
      ow.w = f2bf((o1[4 * rg + 3] * f1 + b2[3] * f2) * inv);
      *(ushort4*)(orow + 32 + 8 * rg + 4 * hi) = ow;
    }
  }
}

// ---------------- launch ----------------
extern "C" void kernel_launch(void* const* d_in, const int* in_sizes, int n_in,
                              void* d_out, int out_size, void* d_ws, size_t ws_size,
                              hipStream_t stream) {
  (void)in_sizes; (void)n_in; (void)out_size; (void)ws_size;
  const float* q_in = (const float*)d_in[0];
  const float* k_in = (const float*)d_in[1];
  const float* v_in = (const float*)d_in[2];
  const float* Wq_w = (const float*)d_in[3];
  const float* Wq_b = (const float*)d_in[4];
  const float* Wk_w = (const float*)d_in[5];
  const float* Wk_b = (const float*)d_in[6];
  const float* Wv_w = (const float*)d_in[7];
  const float* Wv_b = (const float*)d_in[8];
  const float* Wo_w = (const float*)d_in[9];
  const float* Wo_b = (const float*)d_in[10];

  char* ws = (char*)d_ws;
  size_t off = 0;
  auto alloc = [&](size_t n) {
    char* p = ws + off;
    off += (n + 255) & ~(size_t)255;
    return p;
  };
  u16* wT = (u16*)alloc((size_t)4 * FS * HDIM * 2);  // WqT,WkT,WvT,WoT
  u16* QK = (u16*)alloc((size_t)2 * MR * HDIM * 2);  // Qp,Kp contiguous
  u16* VpT = (u16*)alloc((size_t)MR * HDIM * 2);
  u16* Hdp = (u16*)alloc((size_t)MR * HDIM * 2);

  transw4_k<<<dim3(FS / 32, FS / 32, 4), dim3(32, 8), 0, stream>>>(
      Wq_w, Wk_w, Wv_w, Wo_w, wT);

  gemmQKV_k<<<dim3(256, 3), 256, 0, stream>>>(q_in, k_in, v_in, wT, Wq_b,
                                              Wk_b, Wv_b, QK, VpT);

  attn_k<<<BSZ * NH * (SEQ / 128), 512, 0, stream>>>(
      QK, QK + (size_t)MR * HDIM, VpT, Hdp);

  gemm_out_k<<<512, 256, 0, stream>>>(Hdp, wT + (size_t)3 * FS * HDIM, Wo_b,
                                      (float*)d_out);
}

// Round 19
// 112.202 us; speedup vs baseline: 1.1363x; 1.1363x over previous
//
#include <hip/hip_runtime.h>

#define BSZ 2
#define SEQ 2048
#define NH 16
#define DHD 64
#define HDIM 1024   // NH*DHD
#define FS 1024     // input feature size
#define MR (BSZ*SEQ) // 4096
#define L2E 1.4426950408889634f

typedef __bf16 bf16x8 __attribute__((ext_vector_type(8)));
typedef __bf16 bf16x2t __attribute__((ext_vector_type(2)));
typedef float f32x4 __attribute__((ext_vector_type(4)));
typedef float f32x16 __attribute__((ext_vector_type(16)));
typedef unsigned short u16;
typedef unsigned int u32;
typedef u32 u32x4 __attribute__((ext_vector_type(4)));

__device__ __forceinline__ u16 f2bf(float f) {
  u32 x = __float_as_uint(f);
  return (u16)((x + 0x7fffu + ((x >> 16) & 1u)) >> 16);
}

__device__ __forceinline__ u32 pack2bf(float a, float b) {
  bf16x2t t = {(__bf16)a, (__bf16)b};
  return __builtin_bit_cast(u32, t);
}

__device__ __forceinline__ void gload16(const void* g, void* l) {
  __builtin_amdgcn_global_load_lds(
      (const __attribute__((address_space(1))) u32*)g,
      (__attribute__((address_space(3))) u32*)l, 16, 0, 0);
}

// ------- 4x W[K][N] fp32 -> WT[N][K] bf16 (one launch; dsts contiguous) ----
__global__ __launch_bounds__(256) void transw4_k(
    const float* __restrict__ W0, const float* __restrict__ W1,
    const float* __restrict__ W2, const float* __restrict__ W3,
    u16* __restrict__ WTbase) {
  __shared__ float t[32][33];
  const int z = blockIdx.z;
  const float* W = z == 0 ? W0 : z == 1 ? W1 : z == 2 ? W2 : W3;
  u16* WT = WTbase + (size_t)z * FS * HDIM;
  const int tx = threadIdx.x, ty = threadIdx.y;
  const int c0 = blockIdx.x * 32, r0 = blockIdx.y * 32;
#pragma unroll
  for (int i = 0; i < 4; i++)
    t[ty + 8 * i][tx] = W[(size_t)(r0 + ty + 8 * i) * FS + c0 + tx];
  __syncthreads();
#pragma unroll
  for (int i = 0; i < 4; i++)
    WT[(size_t)(c0 + ty + 8 * i) * FS + r0 + tx] = f2bf(t[tx][ty + 8 * i]);
}

// -------- grouped QKV projection GEMM: grid (256, 3) --------
// R16/R17 best-measured version (~33us): fp32 A cast fused into staging;
// bL double-buffered; B(k+1) gload_lds and A(k+1) register loads issued
// AFTER bar1 so their latency hides under the ds_read+MFMA phase and is
// drained by bar2.  48KB LDS keeps 3 blocks/CU (occupancy-bound kernel:
// do NOT trade LDS for fewer barriers -- R14/R18 both regressed).
// Block mapping keeps all 8 n-tiles of an A m-panel on ONE XCD.
__global__ __launch_bounds__(256, 2) void gemmQKV_k(
    const float* __restrict__ qf32, const float* __restrict__ kf32,
    const float* __restrict__ vf32, const u16* __restrict__ WTbase,
    const float* __restrict__ bq, const float* __restrict__ bk,
    const float* __restrict__ bv, u16* __restrict__ QKbase,
    u16* __restrict__ VpT) {
  __shared__ u16 aL[128 * 64];
  __shared__ u16 bL[2][128 * 64];
  const int grp = blockIdx.y;
  const float* Af = grp == 0 ? qf32 : grp == 1 ? kf32 : vf32;
  const u16* BT = WTbase + (size_t)grp * FS * HDIM;
  const float* bias = grp == 0 ? bq : grp == 1 ? bk : bv;
  const int bx = blockIdx.x;
  const int m0 = (4 * (bx & 7) + (bx >> 6)) << 7;   // same-XCD m-panel group
  const int n0 = ((bx >> 3) & 7) << 7;
  const int tid = threadIdx.x, w = tid >> 6, lane = tid & 63;
  const int wr = ((w >> 1) << 6), wc = ((w & 1) << 6);
  const int li = lane & 15, g = lane >> 4;

  f32x4 acc[4][4];
#pragma unroll
  for (int i = 0; i < 4; i++)
#pragma unroll
    for (int j = 0; j < 4; j++) acc[i][j] = (f32x4){0.f, 0.f, 0.f, 0.f};

  // per-chunk sources (constant per thread; step by k)
  const float* asrc[4];
  const u16* bsrc[4];
  int ldoff[4];
#pragma unroll
  for (int j = 0; j < 4; j++) {
    const int c = w * 4 + j;
    const int r = c * 8 + (lane >> 3);
    const int sc = (lane & 7) ^ (r & 7);
    asrc[j] = Af + (size_t)(m0 + r) * FS + sc * 8;
    bsrc[j] = BT + (size_t)(n0 + r) * FS + sc * 8;
    ldoff[j] = c * 1024;
  }

  // prologue: issue B(0) -> bL[0]; load A(0) into registers
  float4 ar0[4], ar1[4];
#pragma unroll
  for (int j = 0; j < 4; j++) gload16(bsrc[j], (char*)bL[0] + ldoff[j]);
#pragma unroll
  for (int j = 0; j < 4; j++) {
    ar0[j] = *(const float4*)(asrc[j]);
    ar1[j] = *(const float4*)(asrc[j] + 4);
  }

  for (int kt = 0; kt < 16; kt++) {
    const int cur = kt & 1;
    // cvt prefetched A regs -> ds_write into aL
#pragma unroll
    for (int j = 0; j < 4; j++) {
      u32x4 pk;
      pk[0] = pack2bf(ar0[j].x, ar0[j].y);
      pk[1] = pack2bf(ar0[j].z, ar0[j].w);
      pk[2] = pack2bf(ar1[j].x, ar1[j].y);
      pk[3] = pack2bf(ar1[j].z, ar1[j].w);
      *(u32x4*)((char*)aL + ldoff[j] + lane * 16) = pk;
    }
    __syncthreads();  // bar1: aL written by all waves, B(kt) drained
    // issue next tile NOW: latency hides under ds_read + MFMA below
    if (kt + 1 < 16) {
      const int ko = (kt + 1) * 64;
#pragma unroll
      for (int j = 0; j < 4; j++)
        gload16(bsrc[j] + ko, (char*)bL[cur ^ 1] + ldoff[j]);
#pragma unroll
      for (int j = 0; j < 4; j++) {
        ar0[j] = *(const float4*)(asrc[j] + ko);
        ar1[j] = *(const float4*)(asrc[j] + ko + 4);
      }
    }
    // ds_read fragments + MFMA
    bf16x8 af[2][4], bfr[2][4];
#pragma unroll
    for (int ks = 0; ks < 2; ks++) {
#pragma unroll
      for (int mf = 0; mf < 4; mf++) {
        const int r = wr + mf * 16 + li;
        const int sl = (g + 4 * ks) ^ (r & 7);
        af[ks][mf] = *(const bf16x8*)((const char*)aL + r * 128 + sl * 16);
      }
#pragma unroll
      for (int nf = 0; nf < 4; nf++) {
        const int r = wc + nf * 16 + li;
        const int sl = (g + 4 * ks) ^ (r & 7);
        bfr[ks][nf] = *(const bf16x8*)((const char*)bL[cur] + r * 128 + sl * 16);
      }
    }
#pragma unroll
    for (int ks = 0; ks < 2; ks++)
#pragma unroll
      for (int mf = 0; mf < 4; mf++)
#pragma unroll
        for (int nf = 0; nf < 4; nf++)
          acc[mf][nf] = __builtin_amdgcn_mfma_f32_16x16x32_bf16(
              af[ks][mf], bfr[ks][nf], acc[mf][nf], 0, 0, 0);
    __syncthreads();  // bar2: aL reads done; drains B(kt+1)/A(kt+1) loads
  }

  if (grp < 2) {
    const float osc = grp == 0 ? 0.125f * L2E : 1.0f;
    u16* C = QKbase + (size_t)grp * MR * HDIM;
#pragma unroll
    for (int mf = 0; mf < 4; mf++)
#pragma unroll
      for (int nf = 0; nf < 4; nf++) {
        const int n = n0 + wc + nf * 16 + li;
        const float bvl = bias[n];
#pragma unroll
        for (int r4 = 0; r4 < 4; r4++) {
          const int m = m0 + wr + mf * 16 + g * 4 + r4;
          C[(size_t)m * HDIM + n] = f2bf((acc[mf][nf][r4] + bvl) * osc);
        }
      }
  } else {
    // V: write transposed per head -> VpT[((b*NH+h)*DHD+d)][kv]
#pragma unroll
    for (int mf = 0; mf < 4; mf++)
#pragma unroll
      for (int nf = 0; nf < 4; nf++) {
        const int n = n0 + wc + nf * 16 + li;
        const float bvl = bias[n];
        const int m = m0 + wr + mf * 16 + g * 4;
        const int bb = m >> 11, kv = m & 2047;
        ushort4 o;
        o.x = f2bf(acc[mf][nf][0] + bvl);
        o.y = f2bf(acc[mf][nf][1] + bvl);
        o.z = f2bf(acc[mf][nf][2] + bvl);
        o.w = f2bf(acc[mf][nf][3] + bvl);
        *(ushort4*)(VpT +
                    ((size_t)(bb * NH + (n >> 6)) * DHD + (n & 63)) * SEQ + kv) = o;
      }
  }
}

// ---------------- output GEMM: out[M][N] = Hd @ WoT^T + bo (fp32) ----------
// R17 version: 128x64 tiles (grid 512 = 2 blocks/CU), full dbuf, one barrier
// per K-step; XCD mapping m=4*(bid&7)+(bid>>7), n=(bid>>3)&15.
__global__ __launch_bounds__(256, 2) void gemm_out_k(
    const u16* __restrict__ A, const u16* __restrict__ BT,
    const float* __restrict__ bias, float* __restrict__ C) {
  __shared__ u16 aL[2][128 * 64];
  __shared__ u16 bL[2][64 * 64];
  const int bx = blockIdx.x;
  const int m0 = ((bx & 7) * 4 + (bx >> 7)) << 7;
  const int n0 = ((bx >> 3) & 15) << 6;
  const int tid = threadIdx.x, w = tid >> 6, lane = tid & 63;
  const int wr = ((w >> 1) << 6), wc = ((w & 1) << 5);  // 2x2 of 64x32
  const int li = lane & 15, g = lane >> 4;

  f32x4 acc[4][2];
#pragma unroll
  for (int i = 0; i < 4; i++)
#pragma unroll
    for (int j = 0; j < 2; j++) acc[i][j] = (f32x4){0.f, 0.f, 0.f, 0.f};

  const u16* asrc[4];
  const u16* bsrc[2];
  int aoff[4], boff[2];
#pragma unroll
  for (int j = 0; j < 4; j++) {
    const int c = w * 4 + j;
    const int r = c * 8 + (lane >> 3);
    const int sc = (lane & 7) ^ (r & 7);
    asrc[j] = A + (size_t)(m0 + r) * HDIM + sc * 8;
    aoff[j] = c * 1024;
  }
#pragma unroll
  for (int j = 0; j < 2; j++) {
    const int c = w * 2 + j;
    const int r = c * 8 + (lane >> 3);
    const int sc = (lane & 7) ^ (r & 7);
    bsrc[j] = BT + (size_t)(n0 + r) * HDIM + sc * 8;
    boff[j] = c * 1024;
  }

  auto stage = [&](int kt, int buf) {
    const int ko = kt * 64;
#pragma unroll
    for (int j = 0; j < 4; j++)
      gload16(asrc[j] + ko, (char*)aL[buf] + aoff[j]);
#pragma unroll
    for (int j = 0; j < 2; j++)
      gload16(bsrc[j] + ko, (char*)bL[buf] + boff[j]);
  };

  stage(0, 0);

  for (int kt = 0; kt < 16; kt++) {
    const int cur = kt & 1;
    __syncthreads();  // drains stage(kt); prev compute reads of cur done
    if (kt + 1 < 16) stage(kt + 1, cur ^ 1);
    bf16x8 af[2][4], bfr[2][2];
#pragma unroll
    for (int ks = 0; ks < 2; ks++) {
#pragma unroll
      for (int mf = 0; mf < 4; mf++) {
        const int r = wr + mf * 16 + li;
        const int sl = (g + 4 * ks) ^ (r & 7);
        af[ks][mf] = *(const bf16x8*)((const char*)aL[cur] + r * 128 + sl * 16);
      }
#pragma unroll
      for (int nf = 0; nf < 2; nf++) {
        const int r = wc + nf * 16 + li;
        const int sl = (g + 4 * ks) ^ (r & 7);
        bfr[ks][nf] = *(const bf16x8*)((const char*)bL[cur] + r * 128 + sl * 16);
      }
    }
#pragma unroll
    for (int ks = 0; ks < 2; ks++)
#pragma unroll
      for (int mf = 0; mf < 4; mf++)
#pragma unroll
        for (int nf = 0; nf < 2; nf++)
          acc[mf][nf] = __builtin_amdgcn_mfma_f32_16x16x32_bf16(
              af[ks][mf], bfr[ks][nf], acc[mf][nf], 0, 0, 0);
  }

#pragma unroll
  for (int mf = 0; mf < 4; mf++)
#pragma unroll
    for (int nf = 0; nf < 2; nf++) {
      const int n = n0 + wc + nf * 16 + li;
      const float bvl = bias[n];
#pragma unroll
      for (int r4 = 0; r4 < 4; r4++) {
        const int m = m0 + wr + mf * 16 + g * 4 + r4;
        C[(size_t)m * HDIM + n] = acc[mf][nf][r4] + bvl;
      }
    }
}

// ------- flash attention: 2-way kv-split, 8 waves, 32x32 MFMA, QBLK=128 ----
// R13/R16 version (best measured: 56.5us).  Frozen.
__global__ __launch_bounds__(512, 1) void attn_k(
    const u16* __restrict__ Qp, const u16* __restrict__ Kp,
    const u16* __restrict__ VpT, u16* __restrict__ Hd) {
  __shared__ u16 kbuf[4][64 * 64];   // K [kv][d], swizzled; [0..1] = Q staging
  __shared__ u16 vbuf[4][64 * 64];   // V^T [d][kv], swizzled

  const int bid = blockIdx.x;
  const int swz = (bid & 7) * 64 + (bid >> 3);  // XCD swizzle (512 = 8*64)
  const int qb = swz & 15;
  const int h = (swz >> 4) & 15;
  const int b = swz >> 8;
  const int tid = threadIdx.x, w = tid >> 6, lane = tid & 63;
  const int sel = w >> 2, g3 = w & 3;
  const int q32 = lane & 31, hi = lane >> 5;
  const int q0 = qb << 7;
  const size_t qbase = (size_t)(b * SEQ + q0) * HDIM + (size_t)h * DHD;
  const size_t kbase = (size_t)(b * SEQ) * HDIM + (size_t)h * DHD;
  const size_t vtbase = (size_t)(b * NH + h) * DHD * SEQ;

  const int rr = lane >> 3;
  const int sc8 = ((lane & 7) ^ rr) * 8;
  const int fkey = (q32 & 7) << 4;

  // ---- stage Q (16KB = kbuf[0..1]) with all 8 waves, read frags, release --
#pragma unroll
  for (int j = 0; j < 2; j++) {
    const int c = w * 2 + j;                // 16 chunks of 8 rows
    const int r = c * 8 + rr;               // q row 0..127
    gload16(Qp + qbase + (size_t)r * HDIM + sc8, (char*)kbuf + c * 1024);
  }
  __syncthreads();
  bf16x8 qf[4];
  {
    const char* qbp = (const char*)kbuf + (g3 * 32 + q32) * 128;
#pragma unroll
    for (int ds = 0; ds < 4; ds++)
      qf[ds] = *(const bf16x8*)(qbp + ((32 * ds + 16 * hi) ^ fkey));
  }
  __syncthreads();

  float mrun = -1e30f, lrun = 0.f;
  f32x16 o0, o1;
#pragma unroll
  for (int i = 0; i < 16; i++) { o0[i] = 0.f; o1[i] = 0.f; }

  // running staging pointers (strength-reduced; advance by const stride)
  const int c0j = g3 * 2;                   // this wave's first chunk
  const int r0r = c0j * 8 + rr;             // its row in the tile
  const u16* kp0 = Kp + kbase + (size_t)(r0r + sel * 64) * HDIM + sc8;
  const u16* kp1 = kp0 + (size_t)8 * HDIM;
  const u16* vp0 = VpT + vtbase + (size_t)r0r * SEQ + sel * 64 + sc8;
  const u16* vp1 = vp0 + (size_t)8 * SEQ;
  const int ldk0 = c0j * 1024, ldk1 = (c0j + 1) * 1024;

  auto stage2 = [&](int buf) {
    gload16(kp0, (char*)kbuf[buf] + ldk0);
    gload16(kp1, (char*)kbuf[buf] + ldk1);
    gload16(vp0, (char*)vbuf[buf] + ldk0);
    gload16(vp1, (char*)vbuf[buf] + ldk1);
    kp0 += (size_t)128 * HDIM;
    kp1 += (size_t)128 * HDIM;
    vp0 += 128;
    vp1 += 128;
  };

  stage2(sel);

#pragma unroll 1
  for (int p = 0; p < SEQ / 128; p++) {
    __syncthreads();  // pair (2p,2p+1) staged; prev reads of those slots done
    if (p + 1 < SEQ / 128) stage2(sel + 2 * ((p + 1) & 1));
    const char* kl = (const char*)kbuf[sel + 2 * (p & 1)];
    const char* vl = (const char*)vbuf[sel + 2 * (p & 1)];

    // ---- S^T = K @ Q^T : C[kv 0-31 | 32-63][q=q32] ----
    f32x16 s0, s1;
#pragma unroll
    for (int i = 0; i < 16; i++) { s0[i] = 0.f; s1[i] = 0.f; }
#pragma unroll
    for (int ds = 0; ds < 4; ds++) {
      const int off = (32 * ds + 16 * hi) ^ fkey;
      const bf16x8 ka = *(const bf16x8*)(kl + q32 * 128 + off);
      const bf16x8 kb2 = *(const bf16x8*)(kl + (32 + q32) * 128 + off);
      s0 = __builtin_amdgcn_mfma_f32_32x32x16_bf16(ka, qf[ds], s0, 0, 0, 0);
      s1 = __builtin_amdgcn_mfma_f32_32x32x16_bf16(kb2, qf[ds], s1, 0, 0, 0);
    }

    // ---- online softmax, tree reductions, defer-max THR=8 (log2 units) ----
    float mt[16];
#pragma unroll
    for (int i = 0; i < 16; i++) mt[i] = fmaxf(s0[i], s1[i]);
#pragma unroll
    for (int i = 0; i < 8; i++) mt[i] = fmaxf(mt[i], mt[i + 8]);
#pragma unroll
    for (int i = 0; i < 4; i++) mt[i] = fmaxf(mt[i], mt[i + 4]);
    float mx = fmaxf(fmaxf(mt[0], mt[1]), fmaxf(mt[2], mt[3]));
    mx = fmaxf(mx, __shfl_xor(mx, 32));
    if (!__all(mx <= mrun + 8.0f)) {
      const float mnew = fmaxf(mrun, mx);
      const float scl = __builtin_amdgcn_exp2f(mrun - mnew);
      mrun = mnew;
      lrun *= scl;
#pragma unroll
      for (int i = 0; i < 16; i++) { o0[i] *= scl; o1[i] *= scl; }
    }
    float p0[16], p1[16];
#pragma unroll
    for (int i = 0; i < 16; i++) {
      p0[i] = __builtin_amdgcn_exp2f(s0[i] - mrun);
      p1[i] = __builtin_amdgcn_exp2f(s1[i] - mrun);
    }
    float st[16];
#pragma unroll
    for (int i = 0; i < 16; i++) st[i] = p0[i] + p1[i];
#pragma unroll
    for (int i = 0; i < 8; i++) st[i] += st[i + 8];
#pragma unroll
    for (int i = 0; i < 4; i++) st[i] += st[i + 4];
    float rs = (st[0] + st[1]) + (st[2] + st[3]);
    rs += __shfl_xor(rs, 32);
    lrun += rs;

    // ---- O^T += V^T @ P^T ; P B-frag via permlane32_swap (verified R7) ----
#pragma unroll
    for (int kvs = 0; kvs < 4; kvs++) {
      const float* ps = (kvs < 2) ? p0 : p1;
      const int rb = (kvs & 1) * 8;
      u32 w01 = pack2bf(ps[rb + 0], ps[rb + 1]);
      u32 w23 = pack2bf(ps[rb + 2], ps[rb + 3]);
      u32 w45 = pack2bf(ps[rb + 4], ps[rb + 5]);
      u32 w67 = pack2bf(ps[rb + 6], ps[rb + 7]);
      asm("v_permlane32_swap_b32 %0, %1" : "+v"(w01), "+v"(w45));
      asm("v_permlane32_swap_b32 %0, %1" : "+v"(w23), "+v"(w67));
      u32x4 uw = {w01, w23, w45, w67};
      const bf16x8 pf = __builtin_bit_cast(bf16x8, uw);
      const int off = (32 * kvs + 16 * hi) ^ fkey;
      const bf16x8 va = *(const bf16x8*)(vl + q32 * 128 + off);
      const bf16x8 vb2 = *(const bf16x8*)(vl + (32 + q32) * 128 + off);
      o0 = __builtin_amdgcn_mfma_f32_32x32x16_bf16(va, pf, o0, 0, 0, 0);
      o1 = __builtin_amdgcn_mfma_f32_32x32x16_bf16(vb2, pf, o1, 0, 0, 0);
    }
  }

  // ---- merge kv-split pairs (waves g3,sel=1 -> g3,sel=0) via LDS ----
  __syncthreads();  // all compute reads of kbuf/vbuf done
  char* mbase = (char*)kbuf + (g3 * 64 + lane) * 144;  // 4*64*144 = 36864 B
  if (sel == 1) {
#pragma unroll
    for (int i = 0; i < 4; i++) {
      *(f32x4*)(mbase + i * 16) =
          (f32x4){o0[4 * i], o0[4 * i + 1], o0[4 * i + 2], o0[4 * i + 3]};
      *(f32x4*)(mbase + 64 + i * 16) =
          (f32x4){o1[4 * i], o1[4 * i + 1], o1[4 * i + 2], o1[4 * i + 3]};
    }
    *(float*)(mbase + 128) = mrun;
    *(float*)(mbase + 132) = lrun;
  }
  __syncthreads();
  if (sel == 0) {
    const float m2 = *(const float*)(mbase + 128);
    const float l2 = *(const float*)(mbase + 132);
    const float ms = fmaxf(mrun, m2);
    const float f1 = __builtin_amdgcn_exp2f(mrun - ms);
    const float f2 = __builtin_amdgcn_exp2f(m2 - ms);
    const float inv = 1.f / (lrun * f1 + l2 * f2);
    const int q = q0 + g3 * 32 + q32;
    u16* orow = Hd + (size_t)(b * SEQ + q) * HDIM + (size_t)h * DHD;
#pragma unroll
    for (int rg = 0; rg < 4; rg++) {
      const f32x4 a2 = *(const f32x4*)(mbase + rg * 16);
      const f32x4 b2 = *(const f32x4*)(mbase + 64 + rg * 16);
      ushort4 ov;
      ov.x = f2bf((o0[4 * rg + 0] * f1 + a2[0] * f2) * inv);
      ov.y = f2bf((o0[4 * rg + 1] * f1 + a2[1] * f2) * inv);
      ov.z = f2bf((o0[4 * rg + 2] * f1 + a2[2] * f2) * inv);
      ov.w = f2bf((o0[4 * rg + 3] * f1 + a2[3] * f2) * inv);
      *(ushort4*)(orow + 8 * rg + 4 * hi) = ov;
      ushort4 ow;
      ow.x = f2bf((o1[4 * rg + 0] * f1 + b2[0] * f2) * inv);
      ow.y = f2bf((o1[4 * rg + 1] * f1 + b2[1] * f2) * inv);
      ow.z = f2bf((o1[4 * rg + 2] * f1 + b2[2] * f2) * inv);
      ow.w = f2bf((o1[4 * rg + 3] * f1 + b2[3] * f2) * inv);
      *(ushort4*)(orow + 32 + 8 * rg + 4 * hi) = ow;
    }
  }
}

// ---------------- launch ----------------
extern "C" void kernel_launch(void* const* d_in, const int* in_sizes, int n_in,
                              void* d_out, int out_size, void* d_ws, size_t ws_size,
                              hipStream_t stream) {
  (void)in_sizes; (void)n_in; (void)out_size; (void)ws_size;
  const float* q_in = (const float*)d_in[0];
  const float* k_in = (const float*)d_in[1];
  const float* v_in = (const float*)d_in[2];
  const float* Wq_w = (const float*)d_in[3];
  const float* Wq_b = (const float*)d_in[4];
  const float* Wk_w = (const float*)d_in[5];
  const float* Wk_b = (const float*)d_in[6];
  const float* Wv_w = (const float*)d_in[7];
  const float* Wv_b = (const float*)d_in[8];
  const float* Wo_w = (const float*)d_in[9];
  const float* Wo_b = (const float*)d_in[10];

  char* ws = (char*)d_ws;
  size_t off = 0;
  auto alloc = [&](size_t n) {
    char* p = ws + off;
    off += (n + 255) & ~(size_t)255;
    return p;
  };
  u16* wT = (u16*)alloc((size_t)4 * FS * HDIM * 2);  // WqT,WkT,WvT,WoT
  u16* QK = (u16*)alloc((size_t)2 * MR * HDIM * 2);  // Qp,Kp contiguous
  u16* VpT = (u16*)alloc((size_t)MR * HDIM * 2);
  u16* Hdp = (u16*)alloc((size_t)MR * HDIM * 2);

  transw4_k<<<dim3(FS / 32, FS / 32, 4), dim3(32, 8), 0, stream>>>(
      Wq_w, Wk_w, Wv_w, Wo_w, wT);

  gemmQKV_k<<<dim3(256, 3), 256, 0, stream>>>(q_in, k_in, v_in, wT, Wq_b,
                                              Wk_b, Wv_b, QK, VpT);

  attn_k<<<BSZ * NH * (SEQ / 128), 512, 0, stream>>>(
      QK, QK + (size_t)MR * HDIM, VpT, Hdp);

  gemm_out_k<<<512, 256, 0, stream>>>(Hdp, wT + (size_t)3 * FS * HDIM, Wo_b,
                                      (float*)d_out);
}

// Round 21
// 112.040 us; speedup vs baseline: 1.1379x; 1.0014x over previous
//
#include <hip/hip_runtime.h>

#define BSZ 2
#define SEQ 2048
#define NH 16
#define DHD 64
#define HDIM 1024   // NH*DHD
#define FS 1024     // input feature size
#define MR (BSZ*SEQ) // 4096
#define L2E 1.4426950408889634f

typedef __bf16 bf16x8 __attribute__((ext_vector_type(8)));
typedef __bf16 bf16x2t __attribute__((ext_vector_type(2)));
typedef float f32x4 __attribute__((ext_vector_type(4)));
typedef float f32x16 __attribute__((ext_vector_type(16)));
typedef unsigned short u16;
typedef unsigned int u32;
typedef u32 u32x4 __attribute__((ext_vector_type(4)));

__device__ __forceinline__ u16 f2bf(float f) {
  u32 x = __float_as_uint(f);
  return (u16)((x + 0x7fffu + ((x >> 16) & 1u)) >> 16);
}

__device__ __forceinline__ u32 pack2bf(float a, float b) {
  bf16x2t t = {(__bf16)a, (__bf16)b};
  return __builtin_bit_cast(u32, t);
}

__device__ __forceinline__ void gload16(const void* g, void* l) {
  __builtin_amdgcn_global_load_lds(
      (const __attribute__((address_space(1))) u32*)g,
      (__attribute__((address_space(3))) u32*)l, 16, 0, 0);
}

// ------- 4x W[K][N] fp32 -> WT[N][K] bf16 (one launch; dsts contiguous) ----
__global__ __launch_bounds__(256) void transw4_k(
    const float* __restrict__ W0, const float* __restrict__ W1,
    const float* __restrict__ W2, const float* __restrict__ W3,
    u16* __restrict__ WTbase) {
  __shared__ float t[32][33];
  const int z = blockIdx.z;
  const float* W = z == 0 ? W0 : z == 1 ? W1 : z == 2 ? W2 : W3;
  u16* WT = WTbase + (size_t)z * FS * HDIM;
  const int tx = threadIdx.x, ty = threadIdx.y;
  const int c0 = blockIdx.x * 32, r0 = blockIdx.y * 32;
#pragma unroll
  for (int i = 0; i < 4; i++)
    t[ty + 8 * i][tx] = W[(size_t)(r0 + ty + 8 * i) * FS + c0 + tx];
  __syncthreads();
#pragma unroll
  for (int i = 0; i < 4; i++)
    WT[(size_t)(c0 + ty + 8 * i) * FS + r0 + tx] = f2bf(t[tx][ty + 8 * i]);
}

// -------- grouped QKV projection GEMM: grid (256, 3) --------
// R16/R17 best-measured version (~33us): fp32 A cast fused into staging;
// bL double-buffered; B(k+1) gload_lds and A(k+1) register loads issued
// AFTER bar1 so their latency hides under the ds_read+MFMA phase and is
// drained by bar2.  48KB LDS keeps 3 blocks/CU (occupancy-bound kernel:
// do NOT trade LDS for fewer barriers -- R14/R18 both regressed).
// Block mapping keeps all 8 n-tiles of an A m-panel on ONE XCD.
__global__ __launch_bounds__(256, 2) void gemmQKV_k(
    const float* __restrict__ qf32, const float* __restrict__ kf32,
    const float* __restrict__ vf32, const u16* __restrict__ WTbase,
    const float* __restrict__ bq, const float* __restrict__ bk,
    const float* __restrict__ bv, u16* __restrict__ QKbase,
    u16* __restrict__ VpT) {
  __shared__ u16 aL[128 * 64];
  __shared__ u16 bL[2][128 * 64];
  const int grp = blockIdx.y;
  const float* Af = grp == 0 ? qf32 : grp == 1 ? kf32 : vf32;
  const u16* BT = WTbase + (size_t)grp * FS * HDIM;
  const float* bias = grp == 0 ? bq : grp == 1 ? bk : bv;
  const int bx = blockIdx.x;
  const int m0 = (4 * (bx & 7) + (bx >> 6)) << 7;   // same-XCD m-panel group
  const int n0 = ((bx >> 3) & 7) << 7;
  const int tid = threadIdx.x, w = tid >> 6, lane = tid & 63;
  const int wr = ((w >> 1) << 6), wc = ((w & 1) << 6);
  const int li = lane & 15, g = lane >> 4;

  f32x4 acc[4][4];
#pragma unroll
  for (int i = 0; i < 4; i++)
#pragma unroll
    for (int j = 0; j < 4; j++) acc[i][j] = (f32x4){0.f, 0.f, 0.f, 0.f};

  // per-chunk sources (constant per thread; step by k)
  const float* asrc[4];
  const u16* bsrc[4];
  int ldoff[4];
#pragma unroll
  for (int j = 0; j < 4; j++) {
    const int c = w * 4 + j;
    const int r = c * 8 + (lane >> 3);
    const int sc = (lane & 7) ^ (r & 7);
    asrc[j] = Af + (size_t)(m0 + r) * FS + sc * 8;
    bsrc[j] = BT + (size_t)(n0 + r) * FS + sc * 8;
    ldoff[j] = c * 1024;
  }

  // prologue: issue B(0) -> bL[0]; load A(0) into registers
  float4 ar0[4], ar1[4];
#pragma unroll
  for (int j = 0; j < 4; j++) gload16(bsrc[j], (char*)bL[0] + ldoff[j]);
#pragma unroll
  for (int j = 0; j < 4; j++) {
    ar0[j] = *(const float4*)(asrc[j]);
    ar1[j] = *(const float4*)(asrc[j] + 4);
  }

  for (int kt = 0; kt < 16; kt++) {
    const int cur = kt & 1;
    // cvt prefetched A regs -> ds_write into aL
#pragma unroll
    for (int j = 0; j < 4; j++) {
      u32x4 pk;
      pk[0] = pack2bf(ar0[j].x, ar0[j].y);
      pk[1] = pack2bf(ar0[j].z, ar0[j].w);
      pk[2] = pack2bf(ar1[j].x, ar1[j].y);
      pk[3] = pack2bf(ar1[j].z, ar1[j].w);
      *(u32x4*)((char*)aL + ldoff[j] + lane * 16) = pk;
    }
    __syncthreads();  // bar1: aL written by all waves, B(kt) drained
    // issue next tile NOW: latency hides under ds_read + MFMA below
    if (kt + 1 < 16) {
      const int ko = (kt + 1) * 64;
#pragma unroll
      for (int j = 0; j < 4; j++)
        gload16(bsrc[j] + ko, (char*)bL[cur ^ 1] + ldoff[j]);
#pragma unroll
      for (int j = 0; j < 4; j++) {
        ar0[j] = *(const float4*)(asrc[j] + ko);
        ar1[j] = *(const float4*)(asrc[j] + ko + 4);
      }
    }
    // ds_read fragments + MFMA
    bf16x8 af[2][4], bfr[2][4];
#pragma unroll
    for (int ks = 0; ks < 2; ks++) {
#pragma unroll
      for (int mf = 0; mf < 4; mf++) {
        const int r = wr + mf * 16 + li;
        const int sl = (g + 4 * ks) ^ (r & 7);
        af[ks][mf] = *(const bf16x8*)((const char*)aL + r * 128 + sl * 16);
      }
#pragma unroll
      for (int nf = 0; nf < 4; nf++) {
        const int r = wc + nf * 16 + li;
        const int sl = (g + 4 * ks) ^ (r & 7);
        bfr[ks][nf] = *(const bf16x8*)((const char*)bL[cur] + r * 128 + sl * 16);
      }
    }
#pragma unroll
    for (int ks = 0; ks < 2; ks++)
#pragma unroll
      for (int mf = 0; mf < 4; mf++)
#pragma unroll
        for (int nf = 0; nf < 4; nf++)
          acc[mf][nf] = __builtin_amdgcn_mfma_f32_16x16x32_bf16(
              af[ks][mf], bfr[ks][nf], acc[mf][nf], 0, 0, 0);
    __syncthreads();  // bar2: aL reads done; drains B(kt+1)/A(kt+1) loads
  }

  if (grp < 2) {
    const float osc = grp == 0 ? 0.125f * L2E : 1.0f;
    u16* C = QKbase + (size_t)grp * MR * HDIM;
#pragma unroll
    for (int mf = 0; mf < 4; mf++)
#pragma unroll
      for (int nf = 0; nf < 4; nf++) {
        const int n = n0 + wc + nf * 16 + li;
        const float bvl = bias[n];
#pragma unroll
        for (int r4 = 0; r4 < 4; r4++) {
          const int m = m0 + wr + mf * 16 + g * 4 + r4;
          C[(size_t)m * HDIM + n] = f2bf((acc[mf][nf][r4] + bvl) * osc);
        }
      }
  } else {
    // V: write transposed per head -> VpT[((b*NH+h)*DHD+d)][kv]
#pragma unroll
    for (int mf = 0; mf < 4; mf++)
#pragma unroll
      for (int nf = 0; nf < 4; nf++) {
        const int n = n0 + wc + nf * 16 + li;
        const float bvl = bias[n];
        const int m = m0 + wr + mf * 16 + g * 4;
        const int bb = m >> 11, kv = m & 2047;
        ushort4 o;
        o.x = f2bf(acc[mf][nf][0] + bvl);
        o.y = f2bf(acc[mf][nf][1] + bvl);
        o.z = f2bf(acc[mf][nf][2] + bvl);
        o.w = f2bf(acc[mf][nf][3] + bvl);
        *(ushort4*)(VpT +
                    ((size_t)(bb * NH + (n >> 6)) * DHD + (n & 63)) * SEQ + kv) = o;
      }
  }
}

// ---------------- output GEMM: out[M][N] = Hd @ WoT^T + bo (fp32) ----------
// R17 version: 128x64 tiles (grid 512 = 2 blocks/CU), full dbuf, one barrier
// per K-step; XCD mapping m=4*(bid&7)+(bid>>7), n=(bid>>3)&15.
__global__ __launch_bounds__(256, 2) void gemm_out_k(
    const u16* __restrict__ A, const u16* __restrict__ BT,
    const float* __restrict__ bias, float* __restrict__ C) {
  __shared__ u16 aL[2][128 * 64];
  __shared__ u16 bL[2][64 * 64];
  const int bx = blockIdx.x;
  const int m0 = ((bx & 7) * 4 + (bx >> 7)) << 7;
  const int n0 = ((bx >> 3) & 15) << 6;
  const int tid = threadIdx.x, w = tid >> 6, lane = tid & 63;
  const int wr = ((w >> 1) << 6), wc = ((w & 1) << 5);  // 2x2 of 64x32
  const int li = lane & 15, g = lane >> 4;

  f32x4 acc[4][2];
#pragma unroll
  for (int i = 0; i < 4; i++)
#pragma unroll
    for (int j = 0; j < 2; j++) acc[i][j] = (f32x4){0.f, 0.f, 0.f, 0.f};

  const u16* asrc[4];
  const u16* bsrc[2];
  int aoff[4], boff[2];
#pragma unroll
  for (int j = 0; j < 4; j++) {
    const int c = w * 4 + j;
    const int r = c * 8 + (lane >> 3);
    const int sc = (lane & 7) ^ (r & 7);
    asrc[j] = A + (size_t)(m0 + r) * HDIM + sc * 8;
    aoff[j] = c * 1024;
  }
#pragma unroll
  for (int j = 0; j < 2; j++) {
    const int c = w * 2 + j;
    const int r = c * 8 + (lane >> 3);
    const int sc = (lane & 7) ^ (r & 7);
    bsrc[j] = BT + (size_t)(n0 + r) * HDIM + sc * 8;
    boff[j] = c * 1024;
  }

  auto stage = [&](int kt, int buf) {
    const int ko = kt * 64;
#pragma unroll
    for (int j = 0; j < 4; j++)
      gload16(asrc[j] + ko, (char*)aL[buf] + aoff[j]);
#pragma unroll
    for (int j = 0; j < 2; j++)
      gload16(bsrc[j] + ko, (char*)bL[buf] + boff[j]);
  };

  stage(0, 0);

  for (int kt = 0; kt < 16; kt++) {
    const int cur = kt & 1;
    __syncthreads();  // drains stage(kt); prev compute reads of cur done
    if (kt + 1 < 16) stage(kt + 1, cur ^ 1);
    bf16x8 af[2][4], bfr[2][2];
#pragma unroll
    for (int ks = 0; ks < 2; ks++) {
#pragma unroll
      for (int mf = 0; mf < 4; mf++) {
        const int r = wr + mf * 16 + li;
        const int sl = (g + 4 * ks) ^ (r & 7);
        af[ks][mf] = *(const bf16x8*)((const char*)aL[cur] + r * 128 + sl * 16);
      }
#pragma unroll
      for (int nf = 0; nf < 2; nf++) {
        const int r = wc + nf * 16 + li;
        const int sl = (g + 4 * ks) ^ (r & 7);
        bfr[ks][nf] = *(const bf16x8*)((const char*)bL[cur] + r * 128 + sl * 16);
      }
    }
#pragma unroll
    for (int ks = 0; ks < 2; ks++)
#pragma unroll
      for (int mf = 0; mf < 4; mf++)
#pragma unroll
        for (int nf = 0; nf < 2; nf++)
          acc[mf][nf] = __builtin_amdgcn_mfma_f32_16x16x32_bf16(
              af[ks][mf], bfr[ks][nf], acc[mf][nf], 0, 0, 0);
  }

#pragma unroll
  for (int mf = 0; mf < 4; mf++)
#pragma unroll
    for (int nf = 0; nf < 2; nf++) {
      const int n = n0 + wc + nf * 16 + li;
      const float bvl = bias[n];
#pragma unroll
      for (int r4 = 0; r4 < 4; r4++) {
        const int m = m0 + wr + mf * 16 + g * 4 + r4;
        C[(size_t)m * HDIM + n] = acc[mf][nf][r4] + bvl;
      }
    }
}

// ------- flash attention: 2-way kv-split, 8 waves, 32x32 MFMA, QBLK=128 ----
// R13/R16 version (best measured: 56.5us).  Frozen.
__global__ __launch_bounds__(512, 1) void attn_k(
    const u16* __restrict__ Qp, const u16* __restrict__ Kp,
    const u16* __restrict__ VpT, u16* __restrict__ Hd) {
  __shared__ u16 kbuf[4][64 * 64];   // K [kv][d], swizzled; [0..1] = Q staging
  __shared__ u16 vbuf[4][64 * 64];   // V^T [d][kv], swizzled

  const int bid = blockIdx.x;
  const int swz = (bid & 7) * 64 + (bid >> 3);  // XCD swizzle (512 = 8*64)
  const int qb = swz & 15;
  const int h = (swz >> 4) & 15;
  const int b = swz >> 8;
  const int tid = threadIdx.x, w = tid >> 6, lane = tid & 63;
  const int sel = w >> 2, g3 = w & 3;
  const int q32 = lane & 31, hi = lane >> 5;
  const int q0 = qb << 7;
  const size_t qbase = (size_t)(b * SEQ + q0) * HDIM + (size_t)h * DHD;
  const size_t kbase = (size_t)(b * SEQ) * HDIM + (size_t)h * DHD;
  const size_t vtbase = (size_t)(b * NH + h) * DHD * SEQ;

  const int rr = lane >> 3;
  const int sc8 = ((lane & 7) ^ rr) * 8;
  const int fkey = (q32 & 7) << 4;

  // ---- stage Q (16KB = kbuf[0..1]) with all 8 waves, read frags, release --
#pragma unroll
  for (int j = 0; j < 2; j++) {
    const int c = w * 2 + j;                // 16 chunks of 8 rows
    const int r = c * 8 + rr;               // q row 0..127
    gload16(Qp + qbase + (size_t)r * HDIM + sc8, (char*)kbuf + c * 1024);
  }
  __syncthreads();
  bf16x8 qf[4];
  {
    const char* qbp = (const char*)kbuf + (g3 * 32 + q32) * 128;
#pragma unroll
    for (int ds = 0; ds < 4; ds++)
      qf[ds] = *(const bf16x8*)(qbp + ((32 * ds + 16 * hi) ^ fkey));
  }
  __syncthreads();

  float mrun = -1e30f, lrun = 0.f;
  f32x16 o0, o1;
#pragma unroll
  for (int i = 0; i < 16; i++) { o0[i] = 0.f; o1[i] = 0.f; }

  // running staging pointers (strength-reduced; advance by const stride)
  const int c0j = g3 * 2;                   // this wave's first chunk
  const int r0r = c0j * 8 + rr;             // its row in the tile
  const u16* kp0 = Kp + kbase + (size_t)(r0r + sel * 64) * HDIM + sc8;
  const u16* kp1 = kp0 + (size_t)8 * HDIM;
  const u16* vp0 = VpT + vtbase + (size_t)r0r * SEQ + sel * 64 + sc8;
  const u16* vp1 = vp0 + (size_t)8 * SEQ;
  const int ldk0 = c0j * 1024, ldk1 = (c0j + 1) * 1024;

  auto stage2 = [&](int buf) {
    gload16(kp0, (char*)kbuf[buf] + ldk0);
    gload16(kp1, (char*)kbuf[buf] + ldk1);
    gload16(vp0, (char*)vbuf[buf] + ldk0);
    gload16(vp1, (char*)vbuf[buf] + ldk1);
    kp0 += (size_t)128 * HDIM;
    kp1 += (size_t)128 * HDIM;
    vp0 += 128;
    vp1 += 128;
  };

  stage2(sel);

#pragma unroll 1
  for (int p = 0; p < SEQ / 128; p++) {
    __syncthreads();  // pair (2p,2p+1) staged; prev reads of those slots done
    if (p + 1 < SEQ / 128) stage2(sel + 2 * ((p + 1) & 1));
    const char* kl = (const char*)kbuf[sel + 2 * (p & 1)];
    const char* vl = (const char*)vbuf[sel + 2 * (p & 1)];

    // ---- S^T = K @ Q^T : C[kv 0-31 | 32-63][q=q32] ----
    f32x16 s0, s1;
#pragma unroll
    for (int i = 0; i < 16; i++) { s0[i] = 0.f; s1[i] = 0.f; }
#pragma unroll
    for (int ds = 0; ds < 4; ds++) {
      const int off = (32 * ds + 16 * hi) ^ fkey;
      const bf16x8 ka = *(const bf16x8*)(kl + q32 * 128 + off);
      const bf16x8 kb2 = *(const bf16x8*)(kl + (32 + q32) * 128 + off);
      s0 = __builtin_amdgcn_mfma_f32_32x32x16_bf16(ka, qf[ds], s0, 0, 0, 0);
      s1 = __builtin_amdgcn_mfma_f32_32x32x16_bf16(kb2, qf[ds], s1, 0, 0, 0);
    }

    // ---- online softmax, tree reductions, defer-max THR=8 (log2 units) ----
    float mt[16];
#pragma unroll
    for (int i = 0; i < 16; i++) mt[i] = fmaxf(s0[i], s1[i]);
#pragma unroll
    for (int i = 0; i < 8; i++) mt[i] = fmaxf(mt[i], mt[i + 8]);
#pragma unroll
    for (int i = 0; i < 4; i++) mt[i] = fmaxf(mt[i], mt[i + 4]);
    float mx = fmaxf(fmaxf(mt[0], mt[1]), fmaxf(mt[2], mt[3]));
    mx = fmaxf(mx, __shfl_xor(mx, 32));
    if (!__all(mx <= mrun + 8.0f)) {
      const float mnew = fmaxf(mrun, mx);
      const float scl = __builtin_amdgcn_exp2f(mrun - mnew);
      mrun = mnew;
      lrun *= scl;
#pragma unroll
      for (int i = 0; i < 16; i++) { o0[i] *= scl; o1[i] *= scl; }
    }
    float p0[16], p1[16];
#pragma unroll
    for (int i = 0; i < 16; i++) {
      p0[i] = __builtin_amdgcn_exp2f(s0[i] - mrun);
      p1[i] = __builtin_amdgcn_exp2f(s1[i] - mrun);
    }
    float st[16];
#pragma unroll
    for (int i = 0; i < 16; i++) st[i] = p0[i] + p1[i];
#pragma unroll
    for (int i = 0; i < 8; i++) st[i] += st[i + 8];
#pragma unroll
    for (int i = 0; i < 4; i++) st[i] += st[i + 4];
    float rs = (st[0] + st[1]) + (st[2] + st[3]);
    rs += __shfl_xor(rs, 32);
    lrun += rs;

    // ---- O^T += V^T @ P^T ; P B-frag via permlane32_swap (verified R7) ----
#pragma unroll
    for (int kvs = 0; kvs < 4; kvs++) {
      const float* ps = (kvs < 2) ? p0 : p1;
      const int rb = (kvs & 1) * 8;
      u32 w01 = pack2bf(ps[rb + 0], ps[rb + 1]);
      u32 w23 = pack2bf(ps[rb + 2], ps[rb + 3]);
      u32 w45 = pack2bf(ps[rb + 4], ps[rb + 5]);
      u32 w67 = pack2bf(ps[rb + 6], ps[rb + 7]);
      asm("v_permlane32_swap_b32 %0, %1" : "+v"(w01), "+v"(w45));
      asm("v_permlane32_swap_b32 %0, %1" : "+v"(w23), "+v"(w67));
      u32x4 uw = {w01, w23, w45, w67};
      const bf16x8 pf = __builtin_bit_cast(bf16x8, uw);
      const int off = (32 * kvs + 16 * hi) ^ fkey;
      const bf16x8 va = *(const bf16x8*)(vl + q32 * 128 + off);
      const bf16x8 vb2 = *(const bf16x8*)(vl + (32 + q32) * 128 + off);
      o0 = __builtin_amdgcn_mfma_f32_32x32x16_bf16(va, pf, o0, 0, 0, 0);
      o1 = __builtin_amdgcn_mfma_f32_32x32x16_bf16(vb2, pf, o1, 0, 0, 0);
    }
  }

  // ---- merge kv-split pairs (waves g3,sel=1 -> g3,sel=0) via LDS ----
  __syncthreads();  // all compute reads of kbuf/vbuf done
  char* mbase = (char*)kbuf + (g3 * 64 + lane) * 144;  // 4*64*144 = 36864 B
  if (sel == 1) {
#pragma unroll
    for (int i = 0; i < 4; i++) {
      *(f32x4*)(mbase + i * 16) =
          (f32x4){o0[4 * i], o0[4 * i + 1], o0[4 * i + 2], o0[4 * i + 3]};
      *(f32x4*)(mbase + 64 + i * 16) =
          (f32x4){o1[4 * i], o1[4 * i + 1], o1[4 * i + 2], o1[4 * i + 3]};
    }
    *(float*)(mbase + 128) = mrun;
    *(float*)(mbase + 132) = lrun;
  }
  __syncthreads();
  if (sel == 0) {
    const float m2 = *(const float*)(mbase + 128);
    const float l2 = *(const float*)(mbase + 132);
    const float ms = fmaxf(mrun, m2);
    const float f1 = __builtin_amdgcn_exp2f(mrun - ms);
    const float f2 = __builtin_amdgcn_exp2f(m2 - ms);
    const float inv = 1.f / (lrun * f1 + l2 * f2);
    const int q = q0 + g3 * 32 + q32;
    u16* orow = Hd + (size_t)(b * SEQ + q) * HDIM + (size_t)h * DHD;
#pragma unroll
    for (int rg = 0; rg < 4; rg++) {
      const f32x4 a2 = *(const f32x4*)(mbase + rg * 16);
      const f32x4 b2 = *(const f32x4*)(mbase + 64 + rg * 16);
      ushort4 ov;
      ov.x = f2bf((o0[4 * rg + 0] * f1 + a2[0] * f2) * inv);
      ov.y = f2bf((o0[4 * rg + 1] * f1 + a2[1] * f2) * inv);
      ov.z = f2bf((o0[4 * rg + 2] * f1 + a2[2] * f2) * inv);
      ov.w = f2bf((o0[4 * rg + 3] * f1 + a2[3] * f2) * inv);
      *(ushort4*)(orow + 8 * rg + 4 * hi) = ov;
      ushort4 ow;
      ow.x = f2bf((o1[4 * rg + 0] * f1 + b2[0] * f2) * inv);
      ow.y = f2bf((o1[4 * rg + 1] * f1 + b2[1] * f2) * inv);
      ow.z = f2bf((o1[4 * rg + 2] * f1 + b2[2] * f2) * inv);
      ow.w = f2bf((o1[4 * rg + 3] * f1 + b2[3] * f2) * inv);
      *(ushort4*)(orow + 32 + 8 * rg + 4 * hi) = ow;
    }
  }
}

// ---------------- launch ----------------
extern "C" void kernel_launch(void* const* d_in, const int* in_sizes, int n_in,
                              void* d_out, int out_size, void* d_ws, size_t ws_size,
                              hipStream_t stream) {
  (void)in_sizes; (void)n_in; (void)out_size; (void)ws_size;
  const float* q_in = (const float*)d_in[0];
  const float* k_in = (const float*)d_in[1];
  const float* v_in = (const float*)d_in[2];
  const float* Wq_w = (const float*)d_in[3];
  const float* Wq_b = (const float*)d_in[4];
  const float* Wk_w = (const float*)d_in[5];
  const float* Wk_b = (const float*)d_in[6];
  const float* Wv_w = (const float*)d_in[7];
  const float* Wv_b = (const float*)d_in[8];
  const float* Wo_w = (const float*)d_in[9];
  const float* Wo_b = (const float*)d_in[10];

  char* ws = (char*)d_ws;
  size_t off = 0;
  auto alloc = [&](size_t n) {
    char* p = ws + off;
    off += (n + 255) & ~(size_t)255;
    return p;
  };
  u16* wT = (u16*)alloc((size_t)4 * FS * HDIM * 2);  // WqT,WkT,WvT,WoT
  u16* QK = (u16*)alloc((size_t)2 * MR * HDIM * 2);  // Qp,Kp contiguous
  u16* VpT = (u16*)alloc((size_t)MR * HDIM * 2);
  u16* Hdp = (u16*)alloc((size_t)MR * HDIM * 2);

  transw4_k<<<dim3(FS / 32, FS / 32, 4), dim3(32, 8), 0, stream>>>(
      Wq_w, Wk_w, Wv_w, Wo_w, wT);

  gemmQKV_k<<<dim3(256, 3), 256, 0, stream>>>(q_in, k_in, v_in, wT, Wq_b,
                                              Wk_b, Wv_b, QK, VpT);

  attn_k<<<BSZ * NH * (SEQ / 128), 512, 0, stream>>>(
      QK, QK + (size_t)MR * HDIM, VpT, Hdp);

  gemm_out_k<<<512, 256, 0, stream>>>(Hdp, wT + (size_t)3 * FS * HDIM, Wo_b,
                                      (float*)d_out);
}